// Round 8
// baseline (464.285 us; speedup 1.0000x reference)
//
#include <hip/hip_runtime.h>
#include <stdint.h>

typedef _Float16 half2_t __attribute__((ext_vector_type(2)));
typedef short bf16x8 __attribute__((ext_vector_type(8)));
typedef float f32x4 __attribute__((ext_vector_type(4)));
typedef int i32x4 __attribute__((ext_vector_type(4)));
typedef int i32x8 __attribute__((ext_vector_type(8)));
typedef unsigned short u16;
typedef unsigned int u32;
typedef unsigned long long u64;

#define B_ 64
#define S_ 512
#define D_ 512
#define H_ 512
#define FF_ 1024
#define C_ 1000
#define V_ 32000

// scaling: W' = 128*Wh (fp4 e2m1), g = 256*h (fp4, >=0).
// g_new = relu(256*xp + (g . W')/128)
#define SW4 128.0f
#define SH4 256.0f

__device__ __forceinline__ u16 f2bf(float f){
  u32 u = __builtin_bit_cast(u32, f);
  u = (u + 0x7FFFu + ((u >> 16) & 1u)) >> 16;
  return (u16)u;
}
__device__ __forceinline__ u32 pkbf(float a, float b){
  return (u32)f2bf(a) | ((u32)f2bf(b) << 16);
}
__device__ __forceinline__ u32 packh2(float a, float b){
  u16 lo = __builtin_bit_cast(u16, (_Float16)a);
  u16 hi = __builtin_bit_cast(u16, (_Float16)b);
  return (u32)lo | ((u32)hi << 16);
}
__device__ __forceinline__ float fdot2u(u32 a, u32 b, float c){
  return __builtin_amdgcn_fdot2(__builtin_bit_cast(half2_t, a),
                                __builtin_bit_cast(half2_t, b), c, false);
}
__device__ __forceinline__ float h2f(u16 h){
  return (float)__builtin_bit_cast(_Float16, h);
}
// decode fp4 e2m1 magnitude code (0..7) -> value {0,.5,1,1.5,2,3,4,6}
__device__ __forceinline__ float fp4val(u32 c){
  int e = (c >> 1) & 3;
  float m = 1.0f + 0.5f * (float)(c & 1);
  return (e == 0) ? 0.5f * (float)(c & 1) : m * (float)(1 << (e - 1));
}

// ---- P0: convert emb table f32 -> bf16 (32000 x 512) ----
__global__ void k_cvt_emb(const float* __restrict__ src, u16* __restrict__ dst){
  int c = blockIdx.x * 256 + threadIdx.x;       // 2,048,000 chunks of 8
  const float4* s = (const float4*)(src + (size_t)c * 8);
  float4 a = s[0], b = s[1];
  uint4 o;
  o.x = pkbf(a.x, a.y); o.y = pkbf(a.z, a.w);
  o.z = pkbf(b.x, b.y); o.w = pkbf(b.z, b.w);
  *(uint4*)(dst + (size_t)c * 8) = o;
}

// ---- P*: fused prep: trans_cvt | prep_w4 | mask | pack W1,W2,Wo ----
// block ranges: [0,64) trans, [64,96) w4, [96,224) mask,
// [224,1248) packW1, [1248,3296) packW2, [3296,5344) packWo
__global__ void k_prep(const float* __restrict__ Wx, u16* __restrict__ WxT,
                       const float* __restrict__ Wh, uint4* __restrict__ Wf4,
                       const int* __restrict__ tokens, unsigned char* __restrict__ masks8,
                       const float* __restrict__ W1, u32* __restrict__ W1p,
                       const float* __restrict__ W2, u32* __restrict__ W2p,
                       const float* __restrict__ Wo, u32* __restrict__ Wop){
  __shared__ u16 t[64][65];
  int bid = blockIdx.x, tid = threadIdx.x;
  if (bid < 64){
    // transpose+convert Wx [512k][512n] -> WxT [512n][512k] bf16
    int bx = bid & 7, by = bid >> 3;
    int c = tid & 63, r0 = (tid >> 6) * 16;
    #pragma unroll
    for (int i = 0; i < 16; i++){
      int k = by * 64 + r0 + i, n = bx * 64 + c;
      t[r0 + i][c] = f2bf(Wx[k * 512 + n]);
    }
    __syncthreads();
    #pragma unroll
    for (int i = 0; i < 16; i++){
      int n = bx * 64 + r0 + i, k = by * 64 + c;
      WxT[n * 512 + k] = t[c][r0 + i];
    }
  } else if (bid < 96){
    // Wh -> fp4 e2m1 (x128) B-fragments for mfma 16x16x128
    int g = (bid - 64) * 256 + tid;            // 8192
    int fidx = g >> 6, l = g & 63;
    int wv = fidx >> 4, ct = (fidx >> 2) & 3, kt = fidx & 3;
    int q = l >> 4, n = wv * 64 + ct * 16 + (l & 15);
    int k0 = kt * 128 + q * 32;
    u32 d[4] = {0u, 0u, 0u, 0u};
    #pragma unroll
    for (int j = 0; j < 32; j++){
      float w = Wh[(size_t)(k0 + j) * 512 + n] * SW4;
      float aw = fabsf(w);
      u32 s = (w < 0.f) ? 8u : 0u;
      u32 c;
      if (aw < 2.f) c = (u32)(int)rintf(aw * 2.f);
      else if (aw < 4.f) c = 4u + (u32)(int)rintf(aw - 2.f);
      else { c = 6u + (u32)(int)rintf((aw - 4.f) * 0.5f); if (c > 7u) c = 7u; }
      d[j >> 3] |= (c | s) << (4 * (j & 7));
    }
    uint4 o; o.x = d[0]; o.y = d[1]; o.z = d[2]; o.w = d[3];
    Wf4[(size_t)fidx * 64 + l] = o;
  } else if (bid < 224){
    int i = (bid - 96) * 256 + tid;            // 32768
    masks8[i] = (tokens[i] != 0) ? 1 : 0;
  } else if (bid < 1248){
    int b2 = bid - 224;                        // W1 [512][1024]: 256 pairs
    int p = b2 >> 2, n = (b2 & 3) * 256 + tid;
    W1p[p * FF_ + n] = packh2(W1[(2 * p) * FF_ + n], W1[(2 * p + 1) * FF_ + n]);
  } else if (bid < 3296){
    int b2 = bid - 1248;                       // W2 [1024][1024]: 512 pairs
    int p = b2 >> 2, n = (b2 & 3) * 256 + tid;
    W2p[p * FF_ + n] = packh2(W2[(2 * p) * FF_ + n], W2[(2 * p + 1) * FF_ + n]);
  } else {
    int b2 = bid - 3296;                       // Wo [1024][1000]: 512 pairs
    int p = b2 >> 2, n = (b2 & 3) * 256 + tid;
    if (n < C_)
      Wop[p * C_ + n] = packh2(Wo[(2 * p) * C_ + n], Wo[(2 * p + 1) * C_ + n]);
  }
}

// ---- G1 v5: xproj = SH4*(gather(embbf,tok) @ Wx + b_rnn). ----
// BM=32, BN=256, 256 thr (4 waves), direct-global MFMA fragments, no LDS.
// ~80 VGPR -> 6 waves/SIMD for load-latency hiding. Grid (1024, 2).
__global__ __launch_bounds__(256) void k_gemm(const int* __restrict__ tokens,
                                              const u16* __restrict__ embbf,
                                              const u16* __restrict__ WxT,
                                              const float* __restrict__ bias,
                                              u16* __restrict__ out){
  int tid = threadIdx.x;
  int m0 = blockIdx.x * 32, n0 = blockIdx.y * 256;
  int w = tid >> 6, l = tid & 63, kg = l >> 4, r16 = l & 15;
  const u16* aptr[2];
  const u16* bptr[4];
  #pragma unroll
  for (int mi = 0; mi < 2; mi++){
    int tok = tokens[m0 + mi * 16 + r16];
    aptr[mi] = embbf + (size_t)tok * 512 + kg * 8;
  }
  #pragma unroll
  for (int ni = 0; ni < 4; ni++)
    bptr[ni] = WxT + (size_t)(n0 + w * 64 + ni * 16 + r16) * 512 + kg * 8;
  f32x4 acc[2][4];
  #pragma unroll
  for (int mi = 0; mi < 2; mi++)
    #pragma unroll
    for (int ni = 0; ni < 4; ni++) acc[mi][ni] = (f32x4){0.f, 0.f, 0.f, 0.f};
  #pragma unroll 4
  for (int kt = 0; kt < 16; kt++){
    bf16x8 af[2], bfr[4];
    #pragma unroll
    for (int mi = 0; mi < 2; mi++)
      af[mi] = *(const bf16x8*)(aptr[mi] + kt * 32);
    #pragma unroll
    for (int ni = 0; ni < 4; ni++)
      bfr[ni] = *(const bf16x8*)(bptr[ni] + kt * 32);
    #pragma unroll
    for (int mi = 0; mi < 2; mi++)
      #pragma unroll
      for (int ni = 0; ni < 4; ni++)
        acc[mi][ni] = __builtin_amdgcn_mfma_f32_16x16x32_bf16(af[mi], bfr[ni], acc[mi][ni], 0, 0, 0);
  }
  #pragma unroll
  for (int ni = 0; ni < 4; ni++){
    int col = n0 + w * 64 + ni * 16 + r16;
    float bb = bias[col];
    #pragma unroll
    for (int mi = 0; mi < 2; mi++){
      int mb = m0 + mi * 16 + kg * 4;
      #pragma unroll
      for (int r = 0; r < 4; r++){
        float v = (acc[mi][ni][r] + bb) * SH4;
        out[(size_t)(mb + r) * 512 + col] = __builtin_bit_cast(u16, (_Float16)v);
      }
    }
  }
}

// ---- R: 512-step RNN scan via MX-fp4 MFMA (K=128). 64 blocks x 512 thr. ----
__global__ __launch_bounds__(512, 2) void k_rnn(
    const uint4* __restrict__ Wf4, const u16* __restrict__ xproj,
    const unsigned char* __restrict__ masks8, u32* __restrict__ hpack){
  __shared__ __align__(16) unsigned char g4[2][256];
  __shared__ unsigned char msk[512];
  int b = blockIdx.x, tid = threadIdx.x;
  int wv = tid >> 6, l = tid & 63, q = l >> 4, n16 = l & 15;
  int col = wv * 64 + q * 16 + n16;

  i32x8 wgt[16];
  #pragma unroll
  for (int ct = 0; ct < 4; ct++)
    #pragma unroll
    for (int kt = 0; kt < 4; kt++){
      int fidx = (wv * 4 + ct) * 4 + kt;
      uint4 wl = Wf4[(size_t)fidx * 64 + l];
      i32x8 w8 = {(int)wl.x, (int)wl.y, (int)wl.z, (int)wl.w, 0, 0, 0, 0};
      wgt[ct * 4 + kt] = w8;
    }

  msk[tid] = masks8[b * 512 + tid];
  if (tid < 64) ((u32*)g4[0])[tid] = 0;
  __syncthreads();

  const u16* xp = xproj + (size_t)b * S_ * H_;
  u16 xraw = xp[col];
  u32 greg = 0;

  #pragma unroll 1
  for (int t = 0; t < 512; t++){
    u16 xnext = 0;
    if (t < 511) xnext = xp[(size_t)(t + 1) * 512 + col];   // prefetch
    bool wr = msk[t] != 0;
    const unsigned char* gc = g4[t & 1];

    f32x4 acc0 = {0.f,0.f,0.f,0.f}, acc1 = {0.f,0.f,0.f,0.f};
    f32x4 acc2 = {0.f,0.f,0.f,0.f}, acc3 = {0.f,0.f,0.f,0.f};
    #pragma unroll
    for (int kt = 0; kt < 4; kt++){
      i32x4 av = *(const i32x4*)(gc + kt * 64 + q * 16);
      i32x8 a8 = {av[0], av[1], av[2], av[3], 0, 0, 0, 0};
      acc0 = __builtin_amdgcn_mfma_scale_f32_16x16x128_f8f6f4(
          a8, wgt[0 * 4 + kt], acc0, 4, 4, 0, 127, 0, 127);
      acc1 = __builtin_amdgcn_mfma_scale_f32_16x16x128_f8f6f4(
          a8, wgt[1 * 4 + kt], acc1, 4, 4, 0, 127, 0, 127);
      acc2 = __builtin_amdgcn_mfma_scale_f32_16x16x128_f8f6f4(
          a8, wgt[2 * 4 + kt], acc2, 4, 4, 0, 127, 0, 127);
      acc3 = __builtin_amdgcn_mfma_scale_f32_16x16x128_f8f6f4(
          a8, wgt[3 * 4 + kt], acc3, 4, 4, 0, 127, 0, 127);
    }

    float av = (q == 0) ? acc0[0] : (q == 1) ? acc1[0] : (q == 2) ? acc2[0] : acc3[0];
    float gn = fmaxf(fmaf(av, 1.0f / SW4, h2f(xraw)), 0.f);
    u32 code;
    if (gn < 2.f) code = (u32)(int)rintf(gn * 2.f);
    else if (gn < 4.f) code = 4u + (u32)(int)rintf(gn - 2.f);
    else { u32 c = 6u + (u32)(int)rintf((gn - 4.f) * 0.5f); code = c > 7u ? 7u : c; }
    u32 pc = (u32)__shfl_xor((int)code, 1);
    u32 byte = (n16 & 1) ? (pc | (code << 4)) : (code | (pc << 4));
    if (wr) greg = byte;
    if ((l & 1) == 0) g4[(t + 1) & 1][col >> 1] = (unsigned char)greg;
    xraw = xnext;
    __syncthreads();
  }

  if (tid < 256){
    u32 byte = g4[0][tid];
    float f0 = fp4val(byte & 15u) * (1.0f / SH4);
    float f1 = fp4val(byte >> 4) * (1.0f / SH4);
    hpack[b * 256 + tid] = packh2(f0, f1);
  }
}

// ---- T: fused fc1+fc2+out+softmax. 64 blocks (1/batch) x 256 threads. ----
__global__ __launch_bounds__(256) void k_tail(const u32* __restrict__ hpack,
    const u32* __restrict__ W1p, const float* __restrict__ b1,
    const u32* __restrict__ W2p, const float* __restrict__ b2,
    const u32* __restrict__ Wop, const float* __restrict__ bo,
    float* __restrict__ out){
  __shared__ __align__(16) u32 rowA[512];
  __shared__ __align__(16) u32 rowB[512];
  __shared__ float redm[4], reds[4];
  int b = blockIdx.x, tid = threadIdx.x;
  rowA[tid] = hpack[b * 256 + tid];
  __syncthreads();

  // fc1: outs n = tid + 256*i, i=0..3; K=256 pairs from rowA[0..255]
  float s0 = 0.f, s1 = 0.f, s2 = 0.f, s3 = 0.f;
  #pragma unroll 2
  for (int p = 0; p < 256; p += 4){
    uint4 h4 = *(const uint4*)&rowA[p];
    const u32* wp = W1p + (size_t)p * FF_ + tid;
    s0 = fdot2u(wp[0], h4.x, s0); s1 = fdot2u(wp[256], h4.x, s1);
    s2 = fdot2u(wp[512], h4.x, s2); s3 = fdot2u(wp[768], h4.x, s3);
    s0 = fdot2u(wp[FF_ + 0], h4.y, s0); s1 = fdot2u(wp[FF_ + 256], h4.y, s1);
    s2 = fdot2u(wp[FF_ + 512], h4.y, s2); s3 = fdot2u(wp[FF_ + 768], h4.y, s3);
    s0 = fdot2u(wp[2*FF_ + 0], h4.z, s0); s1 = fdot2u(wp[2*FF_ + 256], h4.z, s1);
    s2 = fdot2u(wp[2*FF_ + 512], h4.z, s2); s3 = fdot2u(wp[2*FF_ + 768], h4.z, s3);
    s0 = fdot2u(wp[3*FF_ + 0], h4.w, s0); s1 = fdot2u(wp[3*FF_ + 256], h4.w, s1);
    s2 = fdot2u(wp[3*FF_ + 512], h4.w, s2); s3 = fdot2u(wp[3*FF_ + 768], h4.w, s3);
  }
  {
    float y0 = fmaxf(s0 + b1[tid], 0.f);
    float y1 = fmaxf(s1 + b1[tid + 256], 0.f);
    float y2 = fmaxf(s2 + b1[tid + 512], 0.f);
    float y3 = fmaxf(s3 + b1[tid + 768], 0.f);
    float o0 = __shfl_xor(y0, 1), o1 = __shfl_xor(y1, 1);
    float o2 = __shfl_xor(y2, 1), o3 = __shfl_xor(y3, 1);
    if ((tid & 1) == 0){
      int i = tid >> 1;
      rowB[i] = packh2(y0, o0); rowB[128 + i] = packh2(y1, o1);
      rowB[256 + i] = packh2(y2, o2); rowB[384 + i] = packh2(y3, o3);
    }
  }
  __syncthreads();

  // fc2: K=512 pairs from rowB
  s0 = s1 = s2 = s3 = 0.f;
  #pragma unroll 2
  for (int p = 0; p < 512; p += 4){
    uint4 h4 = *(const uint4*)&rowB[p];
    const u32* wp = W2p + (size_t)p * FF_ + tid;
    s0 = fdot2u(wp[0], h4.x, s0); s1 = fdot2u(wp[256], h4.x, s1);
    s2 = fdot2u(wp[512], h4.x, s2); s3 = fdot2u(wp[768], h4.x, s3);
    s0 = fdot2u(wp[FF_ + 0], h4.y, s0); s1 = fdot2u(wp[FF_ + 256], h4.y, s1);
    s2 = fdot2u(wp[FF_ + 512], h4.y, s2); s3 = fdot2u(wp[FF_ + 768], h4.y, s3);
    s0 = fdot2u(wp[2*FF_ + 0], h4.z, s0); s1 = fdot2u(wp[2*FF_ + 256], h4.z, s1);
    s2 = fdot2u(wp[2*FF_ + 512], h4.z, s2); s3 = fdot2u(wp[2*FF_ + 768], h4.z, s3);
    s0 = fdot2u(wp[3*FF_ + 0], h4.w, s0); s1 = fdot2u(wp[3*FF_ + 256], h4.w, s1);
    s2 = fdot2u(wp[3*FF_ + 512], h4.w, s2); s3 = fdot2u(wp[3*FF_ + 768], h4.w, s3);
  }
  {
    float y0 = fmaxf(s0 + b2[tid], 0.f);
    float y1 = fmaxf(s1 + b2[tid + 256], 0.f);
    float y2 = fmaxf(s2 + b2[tid + 512], 0.f);
    float y3 = fmaxf(s3 + b2[tid + 768], 0.f);
    float o0 = __shfl_xor(y0, 1), o1 = __shfl_xor(y1, 1);
    float o2 = __shfl_xor(y2, 1), o3 = __shfl_xor(y3, 1);
    if ((tid & 1) == 0){
      int i = tid >> 1;
      rowA[i] = packh2(y0, o0); rowA[128 + i] = packh2(y1, o1);
      rowA[256 + i] = packh2(y2, o2); rowA[384 + i] = packh2(y3, o3);
    }
  }
  __syncthreads();

  // out: z = y2 @ Wo + bo, softmax over C=1000
  int n0 = tid, n1 = tid + 256, n2 = tid + 512, n3 = tid + 768;
  bool v3 = n3 < C_;
  int n3c = v3 ? n3 : 0;
  float z0 = 0.f, z1 = 0.f, z2 = 0.f, z3 = 0.f;
  #pragma unroll 4
  for (int p = 0; p < 512; p++){
    u32 y = rowA[p];
    z0 = fdot2u(Wop[p * C_ + n0], y, z0);
    z1 = fdot2u(Wop[p * C_ + n1], y, z1);
    z2 = fdot2u(Wop[p * C_ + n2], y, z2);
    z3 = fdot2u(Wop[p * C_ + n3c], y, z3);
  }
  z0 += bo[n0]; z1 += bo[n1]; z2 += bo[n2]; z3 += bo[n3c];
  float mx = fmaxf(fmaxf(z0, z1), z2);
  if (v3) mx = fmaxf(mx, z3);
  #pragma unroll
  for (int o = 1; o < 64; o <<= 1) mx = fmaxf(mx, __shfl_xor(mx, o));
  if ((tid & 63) == 0) redm[tid >> 6] = mx;
  __syncthreads();
  mx = fmaxf(fmaxf(redm[0], redm[1]), fmaxf(redm[2], redm[3]));
  float e0 = __expf(z0 - mx), e1 = __expf(z1 - mx), e2 = __expf(z2 - mx);
  float e3 = v3 ? __expf(z3 - mx) : 0.f;
  float s = e0 + e1 + e2 + e3;
  #pragma unroll
  for (int o = 1; o < 64; o <<= 1) s += __shfl_xor(s, o);
  if ((tid & 63) == 0) reds[tid >> 6] = s;
  __syncthreads();
  s = reds[0] + reds[1] + reds[2] + reds[3];
  float inv = 1.0f / s;
  out[b * C_ + n0] = e0 * inv;
  out[b * C_ + n1] = e1 * inv;
  out[b * C_ + n2] = e2 * inv;
  if (v3) out[b * C_ + n3] = e3 * inv;
}

extern "C" void kernel_launch(void* const* d_in, const int* in_sizes, int n_in,
                              void* d_out, int out_size, void* d_ws, size_t ws_size,
                              hipStream_t stream) {
  const int*   tokens = (const int*)d_in[0];
  const float* emb    = (const float*)d_in[1];
  const float* Wx     = (const float*)d_in[2];
  const float* Wh     = (const float*)d_in[3];
  const float* brnn   = (const float*)d_in[4];
  const float* W1     = (const float*)d_in[5];
  const float* b1     = (const float*)d_in[6];
  const float* W2     = (const float*)d_in[7];
  const float* b2     = (const float*)d_in[8];
  const float* Wo     = (const float*)d_in[9];
  const float* bo     = (const float*)d_in[10];
  float* out = (float*)d_out;

  char* ws = (char*)d_ws;
  size_t off = 0;
  auto alloc = [&](size_t bytes) -> void* {
    void* p = ws + off;
    off += (bytes + 255) & ~(size_t)255;
    return p;
  };
  u16* embbf  = (u16*)alloc((size_t)V_ * 512 * 2);      // emb table, bf16
  u16* WxT    = (u16*)alloc((size_t)512 * 512 * 2);     // Wx transposed, bf16
  u16* xproj  = (u16*)alloc((size_t)32768 * 512 * 2);   // SH4*(x@Wx + b), f16
  uint4* Wf4  = (uint4*)alloc((size_t)128 * 64 * 16);   // Wh fp4 B-fragments
  unsigned char* masks8 = (unsigned char*)alloc(32768); // token!=0 bytes
  u32* W1p    = (u32*)alloc((size_t)256 * 1024 * 4);
  u32* W2p    = (u32*)alloc((size_t)512 * 1024 * 4);
  u32* Wop    = (u32*)alloc((size_t)512 * 1000 * 4);
  u32* hpack  = (u32*)alloc((size_t)64 * 256 * 4);

  k_cvt_emb<<<dim3(8000), dim3(256), 0, stream>>>(emb, embbf);
  k_prep<<<dim3(5344), dim3(256), 0, stream>>>(Wx, WxT, Wh, Wf4, tokens, masks8,
                                               W1, W1p, W2, W2p, Wo, Wop);
  k_gemm<<<dim3(1024, 2), dim3(256), 0, stream>>>(tokens, embbf, WxT, brnn, xproj);
  k_rnn<<<dim3(64), dim3(512), 0, stream>>>(Wf4, xproj, masks8, hpack);
  k_tail<<<dim3(64), dim3(256), 0, stream>>>(hpack, W1p, b1, W2p, b2, Wop, bo, out);
}

// Round 9
// 413.196 us; speedup vs baseline: 1.1236x; 1.1236x over previous
//
#include <hip/hip_runtime.h>
#include <stdint.h>

typedef _Float16 half2_t __attribute__((ext_vector_type(2)));
typedef short bf16x8 __attribute__((ext_vector_type(8)));
typedef float f32x4 __attribute__((ext_vector_type(4)));
typedef int i32x4 __attribute__((ext_vector_type(4)));
typedef int i32x8 __attribute__((ext_vector_type(8)));
typedef unsigned short u16;
typedef unsigned int u32;
typedef unsigned long long u64;

#define B_ 64
#define S_ 512
#define D_ 512
#define H_ 512
#define FF_ 1024
#define C_ 1000
#define V_ 32000

// scaling: W' = 128*Wh (fp4 e2m1), g = 256*h (fp4, >=0).
// g_new = relu(256*xp + (g . W')/128)
#define SW4 128.0f
#define SH4 256.0f

__device__ __forceinline__ u16 f2bf(float f){
  u32 u = __builtin_bit_cast(u32, f);
  u = (u + 0x7FFFu + ((u >> 16) & 1u)) >> 16;
  return (u16)u;
}
__device__ __forceinline__ u32 pkbf(float a, float b){
  return (u32)f2bf(a) | ((u32)f2bf(b) << 16);
}
__device__ __forceinline__ u32 packh2(float a, float b){
  u16 lo = __builtin_bit_cast(u16, (_Float16)a);
  u16 hi = __builtin_bit_cast(u16, (_Float16)b);
  return (u32)lo | ((u32)hi << 16);
}
__device__ __forceinline__ float fdot2u(u32 a, u32 b, float c){
  return __builtin_amdgcn_fdot2(__builtin_bit_cast(half2_t, a),
                                __builtin_bit_cast(half2_t, b), c, false);
}
__device__ __forceinline__ float h2f(u16 h){
  return (float)__builtin_bit_cast(_Float16, h);
}
// decode fp4 e2m1 magnitude code (0..7) -> value {0,.5,1,1.5,2,3,4,6}
__device__ __forceinline__ float fp4val(u32 c){
  int e = (c >> 1) & 3;
  float m = 1.0f + 0.5f * (float)(c & 1);
  return (e == 0) ? 0.5f * (float)(c & 1) : m * (float)(1 << (e - 1));
}

// ---- P*: fused prep: trans_cvt Wx | prep_w4 Wh | pack W1,W2,Wo ----
// block ranges: [0,64) trans, [64,96) w4, [96,1120) packW1,
// [1120,3168) packW2, [3168,5216) packWo
__global__ void k_prep(const float* __restrict__ Wx, u16* __restrict__ WxT,
                       const float* __restrict__ Wh, uint4* __restrict__ Wf4,
                       const float* __restrict__ W1, u32* __restrict__ W1p,
                       const float* __restrict__ W2, u32* __restrict__ W2p,
                       const float* __restrict__ Wo, u32* __restrict__ Wop){
  __shared__ u16 t[64][65];
  int bid = blockIdx.x, tid = threadIdx.x;
  if (bid < 64){
    int bx = bid & 7, by = bid >> 3;
    int c = tid & 63, r0 = (tid >> 6) * 16;
    #pragma unroll
    for (int i = 0; i < 16; i++){
      int k = by * 64 + r0 + i, n = bx * 64 + c;
      t[r0 + i][c] = f2bf(Wx[k * 512 + n]);
    }
    __syncthreads();
    #pragma unroll
    for (int i = 0; i < 16; i++){
      int n = bx * 64 + r0 + i, k = by * 64 + c;
      WxT[n * 512 + k] = t[c][r0 + i];
    }
  } else if (bid < 96){
    int g = (bid - 64) * 256 + tid;            // 8192
    int fidx = g >> 6, l = g & 63;
    int wv = fidx >> 4, ct = (fidx >> 2) & 3, kt = fidx & 3;
    int q = l >> 4, n = wv * 64 + ct * 16 + (l & 15);
    int k0 = kt * 128 + q * 32;
    u32 d[4] = {0u, 0u, 0u, 0u};
    #pragma unroll
    for (int j = 0; j < 32; j++){
      float w = Wh[(size_t)(k0 + j) * 512 + n] * SW4;
      float aw = fabsf(w);
      u32 s = (w < 0.f) ? 8u : 0u;
      u32 c;
      if (aw < 2.f) c = (u32)(int)rintf(aw * 2.f);
      else if (aw < 4.f) c = 4u + (u32)(int)rintf(aw - 2.f);
      else { c = 6u + (u32)(int)rintf((aw - 4.f) * 0.5f); if (c > 7u) c = 7u; }
      d[j >> 3] |= (c | s) << (4 * (j & 7));
    }
    uint4 o; o.x = d[0]; o.y = d[1]; o.z = d[2]; o.w = d[3];
    Wf4[(size_t)fidx * 64 + l] = o;
  } else if (bid < 1120){
    int b2 = bid - 96;                         // W1 [512][1024]: 256 pairs
    int p = b2 >> 2, n = (b2 & 3) * 256 + tid;
    W1p[p * FF_ + n] = packh2(W1[(2 * p) * FF_ + n], W1[(2 * p + 1) * FF_ + n]);
  } else if (bid < 3168){
    int b2 = bid - 1120;                       // W2 [1024][1024]: 512 pairs
    int p = b2 >> 2, n = (b2 & 3) * 256 + tid;
    W2p[p * FF_ + n] = packh2(W2[(2 * p) * FF_ + n], W2[(2 * p + 1) * FF_ + n]);
  } else {
    int b2 = bid - 3168;                       // Wo [1024][1000]: 512 pairs
    int p = b2 >> 2, n = (b2 & 3) * 256 + tid;
    if (n < C_)
      Wop[p * C_ + n] = packh2(Wo[(2 * p) * C_ + n], Wo[(2 * p + 1) * C_ + n]);
  }
}

// ---- G1 v6: vocab GEMM. xpV = SH4*(emb @ Wx + b_rnn), all 32000 rows. ----
// 500 blocks (BM=64) x 512 thr (8 waves); wave w owns cols [w*64,w*64+64).
// A (emb f32) streamed sequentially, converted bf16 during LDS staging.
// B (WxT) direct from global (L2-resident, 512 KB).
__global__ __launch_bounds__(512) void k_gemm(const float* __restrict__ emb,
                                              const u16* __restrict__ WxT,
                                              const float* __restrict__ bias,
                                              u16* __restrict__ xpV){
  __shared__ __align__(16) u16 As[64 * 40];
  int tid = threadIdx.x;
  int m0 = blockIdx.x * 64;
  int w = tid >> 6, l = tid & 63, kg = l >> 4, r16 = l & 15;
  const u16* bptr[4];
  #pragma unroll
  for (int ni = 0; ni < 4; ni++)
    bptr[ni] = WxT + (size_t)(w * 64 + ni * 16 + r16) * 512 + kg * 8;
  f32x4 acc[4][4];
  #pragma unroll
  for (int mi = 0; mi < 4; mi++)
    #pragma unroll
    for (int ni = 0; ni < 4; ni++) acc[mi][ni] = (f32x4){0.f, 0.f, 0.f, 0.f};
  int srow = tid >> 3, sk = (tid & 7) * 4;
  for (int kt = 0; kt < 16; kt++){
    float4 f = *(const float4*)(emb + (size_t)(m0 + srow) * 512 + kt * 32 + sk);
    u32 lo = pkbf(f.x, f.y), hi = pkbf(f.z, f.w);
    __syncthreads();                     // previous k-step's reads complete
    uint2 st; st.x = lo; st.y = hi;
    *(uint2*)(As + srow * 40 + sk) = st;
    __syncthreads();
    bf16x8 bfr[4], af[4];
    #pragma unroll
    for (int ni = 0; ni < 4; ni++)
      bfr[ni] = *(const bf16x8*)(bptr[ni] + kt * 32);
    #pragma unroll
    for (int mi = 0; mi < 4; mi++)
      af[mi] = *(const bf16x8*)(As + (mi * 16 + r16) * 40 + kg * 8);
    #pragma unroll
    for (int mi = 0; mi < 4; mi++)
      #pragma unroll
      for (int ni = 0; ni < 4; ni++)
        acc[mi][ni] = __builtin_amdgcn_mfma_f32_16x16x32_bf16(af[mi], bfr[ni], acc[mi][ni], 0, 0, 0);
  }
  #pragma unroll
  for (int ni = 0; ni < 4; ni++){
    int col = w * 64 + ni * 16 + r16;
    float bb = bias[col];
    #pragma unroll
    for (int mi = 0; mi < 4; mi++){
      int mb = m0 + mi * 16 + kg * 4;
      #pragma unroll
      for (int r = 0; r < 4; r++){
        float v = (acc[mi][ni][r] + bb) * SH4;
        xpV[(size_t)(mb + r) * 512 + col] = __builtin_bit_cast(u16, (_Float16)v);
      }
    }
  }
}

// ---- R: 512-step RNN scan via MX-fp4 MFMA (K=128). 64 blocks x 512 thr. ----
// xp gathered per-step from the vocab projection xpV[tok[t]] (1 KB row
// broadcast, prefetched one full step ahead). Core loop = R6 (proven).
__global__ __launch_bounds__(512, 2) void k_rnn(
    const uint4* __restrict__ Wf4, const u16* __restrict__ xpV,
    const int* __restrict__ tokens, u32* __restrict__ hpack){
  __shared__ __align__(16) unsigned char g4[2][256];
  __shared__ int toks[512];
  int b = blockIdx.x, tid = threadIdx.x;
  int wv = tid >> 6, l = tid & 63, q = l >> 4, n16 = l & 15;
  int col = wv * 64 + q * 16 + n16;

  i32x8 wgt[16];
  #pragma unroll
  for (int ct = 0; ct < 4; ct++)
    #pragma unroll
    for (int kt = 0; kt < 4; kt++){
      int fidx = (wv * 4 + ct) * 4 + kt;
      uint4 wl = Wf4[(size_t)fidx * 64 + l];
      i32x8 w8 = {(int)wl.x, (int)wl.y, (int)wl.z, (int)wl.w, 0, 0, 0, 0};
      wgt[ct * 4 + kt] = w8;
    }

  toks[tid] = tokens[b * 512 + tid];
  if (tid < 64) ((u32*)g4[0])[tid] = 0;
  __syncthreads();

  u16 xraw = xpV[(size_t)toks[0] * 512 + col];
  u32 greg = 0;

  #pragma unroll 1
  for (int t = 0; t < 512; t++){
    int tn = toks[t < 511 ? t + 1 : 0];
    u16 xnext = xpV[(size_t)tn * 512 + col];    // prefetch next step's row
    bool wr = toks[t] != 0;
    const unsigned char* gc = g4[t & 1];

    f32x4 acc0 = {0.f,0.f,0.f,0.f}, acc1 = {0.f,0.f,0.f,0.f};
    f32x4 acc2 = {0.f,0.f,0.f,0.f}, acc3 = {0.f,0.f,0.f,0.f};
    #pragma unroll
    for (int kt = 0; kt < 4; kt++){
      i32x4 av = *(const i32x4*)(gc + kt * 64 + q * 16);
      i32x8 a8 = {av[0], av[1], av[2], av[3], 0, 0, 0, 0};
      acc0 = __builtin_amdgcn_mfma_scale_f32_16x16x128_f8f6f4(
          a8, wgt[0 * 4 + kt], acc0, 4, 4, 0, 127, 0, 127);
      acc1 = __builtin_amdgcn_mfma_scale_f32_16x16x128_f8f6f4(
          a8, wgt[1 * 4 + kt], acc1, 4, 4, 0, 127, 0, 127);
      acc2 = __builtin_amdgcn_mfma_scale_f32_16x16x128_f8f6f4(
          a8, wgt[2 * 4 + kt], acc2, 4, 4, 0, 127, 0, 127);
      acc3 = __builtin_amdgcn_mfma_scale_f32_16x16x128_f8f6f4(
          a8, wgt[3 * 4 + kt], acc3, 4, 4, 0, 127, 0, 127);
    }

    float av = (q == 0) ? acc0[0] : (q == 1) ? acc1[0] : (q == 2) ? acc2[0] : acc3[0];
    float gn = fmaxf(fmaf(av, 1.0f / SW4, h2f(xraw)), 0.f);
    u32 code;
    if (gn < 2.f) code = (u32)(int)rintf(gn * 2.f);
    else if (gn < 4.f) code = 4u + (u32)(int)rintf(gn - 2.f);
    else { u32 c = 6u + (u32)(int)rintf((gn - 4.f) * 0.5f); code = c > 7u ? 7u : c; }
    u32 pc = (u32)__shfl_xor((int)code, 1);
    u32 byte = (n16 & 1) ? (pc | (code << 4)) : (code | (pc << 4));
    if (wr) greg = byte;
    if ((l & 1) == 0) g4[(t + 1) & 1][col >> 1] = (unsigned char)greg;
    xraw = xnext;
    __syncthreads();
  }

  if (tid < 256){
    u32 byte = g4[0][tid];
    float f0 = fp4val(byte & 15u) * (1.0f / SH4);
    float f1 = fp4val(byte >> 4) * (1.0f / SH4);
    hpack[b * 256 + tid] = packh2(f0, f1);
  }
}

// ---- T v2: fused fc1+fc2+out+softmax. 32 blocks x 512 thr, 2 batches/block.
// Each weight load feeds 2 batches (halves L3 traffic to 160 MB, 2x intensity).
__global__ __launch_bounds__(512) void k_tail(const u32* __restrict__ hpack,
    const u32* __restrict__ W1p, const float* __restrict__ b1v,
    const u32* __restrict__ W2p, const float* __restrict__ b2v,
    const u32* __restrict__ Wop, const float* __restrict__ bov,
    float* __restrict__ out){
  __shared__ __align__(16) u32 A0[256], A1[256];
  __shared__ __align__(16) u32 B0[512], B1[512];
  __shared__ __align__(16) u32 C0[512], C1[512];
  __shared__ float redm0[8], redm1[8], reds0[8], reds1[8];
  int ba = blockIdx.x * 2, bb = ba + 1;
  int tid = threadIdx.x, wv = tid >> 6;
  if (tid < 256){ A0[tid] = hpack[ba * 256 + tid]; A1[tid] = hpack[bb * 256 + tid]; }
  __syncthreads();

  // fc1: outs n = tid, tid+512; K=256 pairs
  float a00 = 0.f, a01 = 0.f, a10 = 0.f, a11 = 0.f;
  #pragma unroll 4
  for (int p = 0; p < 256; p += 2){
    u32 h00 = A0[p], h01 = A0[p + 1], h10 = A1[p], h11 = A1[p + 1];
    const u32* wp = W1p + (size_t)p * FF_ + tid;
    u32 w0 = wp[0], w1 = wp[512], w0b = wp[FF_], w1b = wp[FF_ + 512];
    a00 = fdot2u(w0, h00, a00);  a01 = fdot2u(w1, h00, a01);
    a10 = fdot2u(w0, h10, a10);  a11 = fdot2u(w1, h10, a11);
    a00 = fdot2u(w0b, h01, a00); a01 = fdot2u(w1b, h01, a01);
    a10 = fdot2u(w0b, h11, a10); a11 = fdot2u(w1b, h11, a11);
  }
  {
    float blo = b1v[tid], bhi = b1v[tid + 512];
    float y00 = fmaxf(a00 + blo, 0.f), y01 = fmaxf(a01 + bhi, 0.f);
    float y10 = fmaxf(a10 + blo, 0.f), y11 = fmaxf(a11 + bhi, 0.f);
    float o00 = __shfl_xor(y00, 1), o01 = __shfl_xor(y01, 1);
    float o10 = __shfl_xor(y10, 1), o11 = __shfl_xor(y11, 1);
    if (!(tid & 1)){
      int i = tid >> 1;
      B0[i] = packh2(y00, o00); B0[256 + i] = packh2(y01, o01);
      B1[i] = packh2(y10, o10); B1[256 + i] = packh2(y11, o11);
    }
  }
  __syncthreads();

  // fc2: outs n = tid, tid+512; K=512 pairs
  a00 = a01 = a10 = a11 = 0.f;
  #pragma unroll 4
  for (int p = 0; p < 512; p += 2){
    u32 h00 = B0[p], h01 = B0[p + 1], h10 = B1[p], h11 = B1[p + 1];
    const u32* wp = W2p + (size_t)p * FF_ + tid;
    u32 w0 = wp[0], w1 = wp[512], w0b = wp[FF_], w1b = wp[FF_ + 512];
    a00 = fdot2u(w0, h00, a00);  a01 = fdot2u(w1, h00, a01);
    a10 = fdot2u(w0, h10, a10);  a11 = fdot2u(w1, h10, a11);
    a00 = fdot2u(w0b, h01, a00); a01 = fdot2u(w1b, h01, a01);
    a10 = fdot2u(w0b, h11, a10); a11 = fdot2u(w1b, h11, a11);
  }
  {
    float blo = b2v[tid], bhi = b2v[tid + 512];
    float y00 = fmaxf(a00 + blo, 0.f), y01 = fmaxf(a01 + bhi, 0.f);
    float y10 = fmaxf(a10 + blo, 0.f), y11 = fmaxf(a11 + bhi, 0.f);
    float o00 = __shfl_xor(y00, 1), o01 = __shfl_xor(y01, 1);
    float o10 = __shfl_xor(y10, 1), o11 = __shfl_xor(y11, 1);
    if (!(tid & 1)){
      int i = tid >> 1;
      C0[i] = packh2(y00, o00); C0[256 + i] = packh2(y01, o01);
      C1[i] = packh2(y10, o10); C1[256 + i] = packh2(y11, o11);
    }
  }
  __syncthreads();

  // out: z = y2 @ Wo + bo, softmax over C=1000; outs n = tid, tid+512
  int n1 = tid + 512;
  bool v1 = n1 < C_;
  int n1c = v1 ? n1 : 0;
  float z00 = 0.f, z01 = 0.f, z10 = 0.f, z11 = 0.f;
  #pragma unroll 4
  for (int p = 0; p < 512; p++){
    u32 y0 = C0[p], y1 = C1[p];
    u32 w0 = Wop[(size_t)p * C_ + tid], w1 = Wop[(size_t)p * C_ + n1c];
    z00 = fdot2u(w0, y0, z00); z01 = fdot2u(w1, y0, z01);
    z10 = fdot2u(w0, y1, z10); z11 = fdot2u(w1, y1, z11);
  }
  z00 += bov[tid]; z10 += bov[tid];
  z01 += bov[n1c]; z11 += bov[n1c];
  float mx0 = fmaxf(z00, v1 ? z01 : -1e30f);
  float mx1 = fmaxf(z10, v1 ? z11 : -1e30f);
  #pragma unroll
  for (int o = 1; o < 64; o <<= 1){
    mx0 = fmaxf(mx0, __shfl_xor(mx0, o));
    mx1 = fmaxf(mx1, __shfl_xor(mx1, o));
  }
  if ((tid & 63) == 0){ redm0[wv] = mx0; redm1[wv] = mx1; }
  __syncthreads();
  mx0 = redm0[0]; mx1 = redm1[0];
  #pragma unroll
  for (int i = 1; i < 8; i++){
    mx0 = fmaxf(mx0, redm0[i]);
    mx1 = fmaxf(mx1, redm1[i]);
  }
  float e00 = __expf(z00 - mx0), e01 = v1 ? __expf(z01 - mx0) : 0.f;
  float e10 = __expf(z10 - mx1), e11 = v1 ? __expf(z11 - mx1) : 0.f;
  float s0 = e00 + e01, s1 = e10 + e11;
  #pragma unroll
  for (int o = 1; o < 64; o <<= 1){
    s0 += __shfl_xor(s0, o);
    s1 += __shfl_xor(s1, o);
  }
  if ((tid & 63) == 0){ reds0[wv] = s0; reds1[wv] = s1; }
  __syncthreads();
  s0 = 0.f; s1 = 0.f;
  #pragma unroll
  for (int i = 0; i < 8; i++){ s0 += reds0[i]; s1 += reds1[i]; }
  float inv0 = 1.0f / s0, inv1 = 1.0f / s1;
  out[(size_t)ba * C_ + tid] = e00 * inv0;
  out[(size_t)bb * C_ + tid] = e10 * inv1;
  if (v1){
    out[(size_t)ba * C_ + n1] = e01 * inv0;
    out[(size_t)bb * C_ + n1] = e11 * inv1;
  }
}

extern "C" void kernel_launch(void* const* d_in, const int* in_sizes, int n_in,
                              void* d_out, int out_size, void* d_ws, size_t ws_size,
                              hipStream_t stream) {
  const int*   tokens = (const int*)d_in[0];
  const float* emb    = (const float*)d_in[1];
  const float* Wx     = (const float*)d_in[2];
  const float* Wh     = (const float*)d_in[3];
  const float* brnn   = (const float*)d_in[4];
  const float* W1     = (const float*)d_in[5];
  const float* b1     = (const float*)d_in[6];
  const float* W2     = (const float*)d_in[7];
  const float* b2     = (const float*)d_in[8];
  const float* Wo     = (const float*)d_in[9];
  const float* bo     = (const float*)d_in[10];
  float* out = (float*)d_out;

  char* ws = (char*)d_ws;
  size_t off = 0;
  auto alloc = [&](size_t bytes) -> void* {
    void* p = ws + off;
    off += (bytes + 255) & ~(size_t)255;
    return p;
  };
  u16* WxT    = (u16*)alloc((size_t)512 * 512 * 2);     // Wx transposed, bf16
  u16* xpV    = (u16*)alloc((size_t)V_ * 512 * 2);      // SH4*(emb@Wx+b), f16, per vocab
  uint4* Wf4  = (uint4*)alloc((size_t)128 * 64 * 16);   // Wh fp4 B-fragments
  u32* W1p    = (u32*)alloc((size_t)256 * 1024 * 4);
  u32* W2p    = (u32*)alloc((size_t)512 * 1024 * 4);
  u32* Wop    = (u32*)alloc((size_t)512 * 1000 * 4);
  u32* hpack  = (u32*)alloc((size_t)64 * 256 * 4);

  k_prep<<<dim3(5216), dim3(256), 0, stream>>>(Wx, WxT, Wh, Wf4,
                                               W1, W1p, W2, W2p, Wo, Wop);
  k_gemm<<<dim3(500), dim3(512), 0, stream>>>(emb, WxT, brnn, xpV);
  k_rnn<<<dim3(64), dim3(512), 0, stream>>>(Wf4, xpV, tokens, hpack);
  k_tail<<<dim3(32), dim3(512), 0, stream>>>(hpack, W1p, b1, W2p, b2, Wop, bo, out);
}

// Round 10
// 386.469 us; speedup vs baseline: 1.2014x; 1.0692x over previous
//
#include <hip/hip_runtime.h>
#include <stdint.h>

typedef _Float16 half2_t __attribute__((ext_vector_type(2)));
typedef short bf16x8 __attribute__((ext_vector_type(8)));
typedef float f32x4 __attribute__((ext_vector_type(4)));
typedef int i32x4 __attribute__((ext_vector_type(4)));
typedef int i32x8 __attribute__((ext_vector_type(8)));
typedef unsigned short u16;
typedef unsigned int u32;
typedef unsigned long long u64;

#define B_ 64
#define S_ 512
#define D_ 512
#define H_ 512
#define FF_ 1024
#define C_ 1000
#define V_ 32000

// scaling: W' = 128*Wh (fp4 e2m1), g = 256*h (fp4, >=0).
#define SW4 128.0f
#define SH4 256.0f

__device__ __forceinline__ u16 f2bf(float f){
  u32 u = __builtin_bit_cast(u32, f);
  u = (u + 0x7FFFu + ((u >> 16) & 1u)) >> 16;
  return (u16)u;
}
__device__ __forceinline__ u32 pkbf(float a, float b){
  return (u32)f2bf(a) | ((u32)f2bf(b) << 16);
}
__device__ __forceinline__ u32 packh2(float a, float b){
  u16 lo = __builtin_bit_cast(u16, (_Float16)a);
  u16 hi = __builtin_bit_cast(u16, (_Float16)b);
  return (u32)lo | ((u32)hi << 16);
}
__device__ __forceinline__ float fdot2u(u32 a, u32 b, float c){
  return __builtin_amdgcn_fdot2(__builtin_bit_cast(half2_t, a),
                                __builtin_bit_cast(half2_t, b), c, false);
}
__device__ __forceinline__ float h2f(u16 h){
  return (float)__builtin_bit_cast(_Float16, h);
}
__device__ __forceinline__ float fp4val(u32 c){
  int e = (c >> 1) & 3;
  float m = 1.0f + 0.5f * (float)(c & 1);
  return (e == 0) ? 0.5f * (float)(c & 1) : m * (float)(1 << (e - 1));
}

// ---- P: Wx transpose+cvt [0,64) | Wh fp4 fragments [64,96) ----
__global__ void k_prep(const float* __restrict__ Wx, u16* __restrict__ WxT,
                       const float* __restrict__ Wh, uint4* __restrict__ Wf4){
  __shared__ u16 t[64][65];
  int bid = blockIdx.x, tid = threadIdx.x;
  if (bid < 64){
    int bx = bid & 7, by = bid >> 3;
    int c = tid & 63, r0 = (tid >> 6) * 16;
    #pragma unroll
    for (int i = 0; i < 16; i++){
      int k = by * 64 + r0 + i, n = bx * 64 + c;
      t[r0 + i][c] = f2bf(Wx[k * 512 + n]);
    }
    __syncthreads();
    #pragma unroll
    for (int i = 0; i < 16; i++){
      int n = bx * 64 + r0 + i, k = by * 64 + c;
      WxT[n * 512 + k] = t[c][r0 + i];
    }
  } else {
    int g = (bid - 64) * 256 + tid;            // 8192
    int fidx = g >> 6, l = g & 63;
    int wv = fidx >> 4, ct = (fidx >> 2) & 3, kt = fidx & 3;
    int q = l >> 4, n = wv * 64 + ct * 16 + (l & 15);
    int k0 = kt * 128 + q * 32;
    u32 d[4] = {0u, 0u, 0u, 0u};
    #pragma unroll
    for (int j = 0; j < 32; j++){
      float w = Wh[(size_t)(k0 + j) * 512 + n] * SW4;
      float aw = fabsf(w);
      u32 s = (w < 0.f) ? 8u : 0u;
      u32 c;
      if (aw < 2.f) c = (u32)(int)rintf(aw * 2.f);
      else if (aw < 4.f) c = 4u + (u32)(int)rintf(aw - 2.f);
      else { c = 6u + (u32)(int)rintf((aw - 4.f) * 0.5f); if (c > 7u) c = 7u; }
      d[j >> 3] |= (c | s) << (4 * (j & 7));
    }
    uint4 o; o.x = d[0]; o.y = d[1]; o.z = d[2]; o.w = d[3];
    Wf4[(size_t)fidx * 64 + l] = o;
  }
}

// ---- G: vocab GEMM [0,500) with reg double-buffered A stream, plus
// weight packs as extra blocks: W1 [500,1012), W2 [1012,2036), Wo [2036,3060).
__global__ __launch_bounds__(512) void k_gemm(const float* __restrict__ emb,
                                              const u16* __restrict__ WxT,
                                              const float* __restrict__ bias,
                                              u16* __restrict__ xpV,
                                              const float* __restrict__ W1, u32* __restrict__ W1p,
                                              const float* __restrict__ W2, u32* __restrict__ W2p,
                                              const float* __restrict__ Wo, u32* __restrict__ Wop){
  __shared__ __align__(16) u16 As[64 * 40];
  int bid = blockIdx.x, tid = threadIdx.x;
  if (bid >= 500){
    if (bid < 1012){
      int i = (bid - 500) * 512 + tid;         // 262144 = 256p x 1024n
      int p = i >> 10, n = i & 1023;
      W1p[p * FF_ + n] = packh2(W1[(2 * p) * FF_ + n], W1[(2 * p + 1) * FF_ + n]);
    } else if (bid < 2036){
      int i = (bid - 1012) * 512 + tid;        // 524288 = 512p x 1024n
      int p = i >> 10, n = i & 1023;
      W2p[p * FF_ + n] = packh2(W2[(2 * p) * FF_ + n], W2[(2 * p + 1) * FF_ + n]);
    } else {
      int i = (bid - 2036) * 512 + tid;        // 512p x 1024 (n<1000 valid)
      int p = i >> 10, n = i & 1023;
      if (n < C_)
        Wop[p * C_ + n] = packh2(Wo[(2 * p) * C_ + n], Wo[(2 * p + 1) * C_ + n]);
    }
    return;
  }
  int m0 = bid * 64;
  int w = tid >> 6, l = tid & 63, kg = l >> 4, r16 = l & 15;
  const u16* bptr[4];
  #pragma unroll
  for (int ni = 0; ni < 4; ni++)
    bptr[ni] = WxT + (size_t)(w * 64 + ni * 16 + r16) * 512 + kg * 8;
  f32x4 acc[4][4];
  #pragma unroll
  for (int mi = 0; mi < 4; mi++)
    #pragma unroll
    for (int ni = 0; ni < 4; ni++) acc[mi][ni] = (f32x4){0.f, 0.f, 0.f, 0.f};
  int srow = tid >> 3, sk = (tid & 7) * 4;
  const float* ebase = emb + (size_t)(m0 + srow) * 512 + sk;
  float4 f = *(const float4*)ebase;            // kt = 0
  for (int kt = 0; kt < 16; kt++){
    u32 lo = pkbf(f.x, f.y), hi = pkbf(f.z, f.w);
    float4 fn;
    if (kt < 15) fn = *(const float4*)(ebase + (kt + 1) * 32);   // prefetch
    __syncthreads();
    uint2 st; st.x = lo; st.y = hi;
    *(uint2*)(As + srow * 40 + sk) = st;
    __syncthreads();
    bf16x8 bfr[4], af[4];
    #pragma unroll
    for (int ni = 0; ni < 4; ni++)
      bfr[ni] = *(const bf16x8*)(bptr[ni] + kt * 32);
    #pragma unroll
    for (int mi = 0; mi < 4; mi++)
      af[mi] = *(const bf16x8*)(As + (mi * 16 + r16) * 40 + kg * 8);
    #pragma unroll
    for (int mi = 0; mi < 4; mi++)
      #pragma unroll
      for (int ni = 0; ni < 4; ni++)
        acc[mi][ni] = __builtin_amdgcn_mfma_f32_16x16x32_bf16(af[mi], bfr[ni], acc[mi][ni], 0, 0, 0);
    f = fn;
  }
  #pragma unroll
  for (int ni = 0; ni < 4; ni++){
    int col = w * 64 + ni * 16 + r16;
    float bb = bias[col];
    #pragma unroll
    for (int mi = 0; mi < 4; mi++){
      int mb = m0 + mi * 16 + kg * 4;
      #pragma unroll
      for (int r = 0; r < 4; r++){
        float v = (acc[mi][ni][r] + bb) * SH4;
        xpV[(size_t)(mb + r) * 512 + col] = __builtin_bit_cast(u16, (_Float16)v);
      }
    }
  }
}

// ---- R: 512-step RNN scan via MX-fp4 MFMA (K=128). UNCHANGED (control). ----
__global__ __launch_bounds__(512, 2) void k_rnn(
    const uint4* __restrict__ Wf4, const u16* __restrict__ xpV,
    const int* __restrict__ tokens, u32* __restrict__ hpack){
  __shared__ __align__(16) unsigned char g4[2][256];
  __shared__ int toks[512];
  int b = blockIdx.x, tid = threadIdx.x;
  int wv = tid >> 6, l = tid & 63, q = l >> 4, n16 = l & 15;
  int col = wv * 64 + q * 16 + n16;

  i32x8 wgt[16];
  #pragma unroll
  for (int ct = 0; ct < 4; ct++)
    #pragma unroll
    for (int kt = 0; kt < 4; kt++){
      int fidx = (wv * 4 + ct) * 4 + kt;
      uint4 wl = Wf4[(size_t)fidx * 64 + l];
      i32x8 w8 = {(int)wl.x, (int)wl.y, (int)wl.z, (int)wl.w, 0, 0, 0, 0};
      wgt[ct * 4 + kt] = w8;
    }

  toks[tid] = tokens[b * 512 + tid];
  if (tid < 64) ((u32*)g4[0])[tid] = 0;
  __syncthreads();

  u16 xraw = xpV[(size_t)toks[0] * 512 + col];
  u32 greg = 0;

  #pragma unroll 1
  for (int t = 0; t < 512; t++){
    int tn = toks[t < 511 ? t + 1 : 0];
    u16 xnext = xpV[(size_t)tn * 512 + col];
    bool wr = toks[t] != 0;
    const unsigned char* gc = g4[t & 1];

    f32x4 acc0 = {0.f,0.f,0.f,0.f}, acc1 = {0.f,0.f,0.f,0.f};
    f32x4 acc2 = {0.f,0.f,0.f,0.f}, acc3 = {0.f,0.f,0.f,0.f};
    #pragma unroll
    for (int kt = 0; kt < 4; kt++){
      i32x4 av = *(const i32x4*)(gc + kt * 64 + q * 16);
      i32x8 a8 = {av[0], av[1], av[2], av[3], 0, 0, 0, 0};
      acc0 = __builtin_amdgcn_mfma_scale_f32_16x16x128_f8f6f4(
          a8, wgt[0 * 4 + kt], acc0, 4, 4, 0, 127, 0, 127);
      acc1 = __builtin_amdgcn_mfma_scale_f32_16x16x128_f8f6f4(
          a8, wgt[1 * 4 + kt], acc1, 4, 4, 0, 127, 0, 127);
      acc2 = __builtin_amdgcn_mfma_scale_f32_16x16x128_f8f6f4(
          a8, wgt[2 * 4 + kt], acc2, 4, 4, 0, 127, 0, 127);
      acc3 = __builtin_amdgcn_mfma_scale_f32_16x16x128_f8f6f4(
          a8, wgt[3 * 4 + kt], acc3, 4, 4, 0, 127, 0, 127);
    }

    float av = (q == 0) ? acc0[0] : (q == 1) ? acc1[0] : (q == 2) ? acc2[0] : acc3[0];
    float gn = fmaxf(fmaf(av, 1.0f / SW4, h2f(xraw)), 0.f);
    u32 code;
    if (gn < 2.f) code = (u32)(int)rintf(gn * 2.f);
    else if (gn < 4.f) code = 4u + (u32)(int)rintf(gn - 2.f);
    else { u32 c = 6u + (u32)(int)rintf((gn - 4.f) * 0.5f); code = c > 7u ? 7u : c; }
    u32 pc = (u32)__shfl_xor((int)code, 1);
    u32 byte = (n16 & 1) ? (pc | (code << 4)) : (code | (pc << 4));
    if (wr) greg = byte;
    if ((l & 1) == 0) g4[(t + 1) & 1][col >> 1] = (unsigned char)greg;
    xraw = xnext;
    __syncthreads();
  }

  if (tid < 256){
    u32 byte = g4[0][tid];
    float f0 = fp4val(byte & 15u) * (1.0f / SH4);
    float f1 = fp4val(byte >> 4) * (1.0f / SH4);
    hpack[b * 256 + tid] = packh2(f0, f1);
  }
}

// ---- F1: y1 = relu(h @ W1 + b1). grid (4 nslices, 32 batch-pairs). ----
__global__ __launch_bounds__(256) void k_fc1(const u32* __restrict__ hpack,
    const u32* __restrict__ W1p, const float* __restrict__ b1, u32* __restrict__ y1p){
  __shared__ u32 h0[256], h1[256];
  int nx = blockIdx.x, bp = blockIdx.y, tid = threadIdx.x;
  int ba = bp * 2, bb = ba + 1;
  int n = nx * 256 + tid;
  h0[tid] = hpack[ba * 256 + tid];
  h1[tid] = hpack[bb * 256 + tid];
  __syncthreads();
  float a0 = 0.f, a1 = 0.f;
  #pragma unroll 8
  for (int p = 0; p < 256; p++){
    u32 w = W1p[p * FF_ + n];
    a0 = fdot2u(w, h0[p], a0);
    a1 = fdot2u(w, h1[p], a1);
  }
  float bbv = b1[n];
  float y0 = fmaxf(a0 + bbv, 0.f), y1 = fmaxf(a1 + bbv, 0.f);
  float o0 = __shfl_xor(y0, 1), o1 = __shfl_xor(y1, 1);
  if (!(tid & 1)){
    y1p[ba * 512 + (n >> 1)] = packh2(y0, o0);
    y1p[bb * 512 + (n >> 1)] = packh2(y1, o1);
  }
}

// ---- F2: y2 = relu(y1 @ W2 + b2). grid (4, 32). ----
__global__ __launch_bounds__(256) void k_fc2(const u32* __restrict__ y1p,
    const u32* __restrict__ W2p, const float* __restrict__ b2, u32* __restrict__ y2p){
  __shared__ u32 h0[512], h1[512];
  int nx = blockIdx.x, bp = blockIdx.y, tid = threadIdx.x;
  int ba = bp * 2, bb = ba + 1;
  int n = nx * 256 + tid;
  h0[tid] = y1p[ba * 512 + tid];       h1[tid] = y1p[bb * 512 + tid];
  h0[tid + 256] = y1p[ba * 512 + 256 + tid];
  h1[tid + 256] = y1p[bb * 512 + 256 + tid];
  __syncthreads();
  float a0 = 0.f, a1 = 0.f;
  #pragma unroll 8
  for (int p = 0; p < 512; p++){
    u32 w = W2p[p * FF_ + n];
    a0 = fdot2u(w, h0[p], a0);
    a1 = fdot2u(w, h1[p], a1);
  }
  float bbv = b2[n];
  float y0 = fmaxf(a0 + bbv, 0.f), y1 = fmaxf(a1 + bbv, 0.f);
  float o0 = __shfl_xor(y0, 1), o1 = __shfl_xor(y1, 1);
  if (!(tid & 1)){
    y2p[ba * 512 + (n >> 1)] = packh2(y0, o0);
    y2p[bb * 512 + (n >> 1)] = packh2(y1, o1);
  }
}

// ---- OZ: z = y2 @ Wo + bo (logits, f32). grid (4 cslices, 32 pairs). ----
__global__ __launch_bounds__(256) void k_outz(const u32* __restrict__ y2p,
    const u32* __restrict__ Wop, const float* __restrict__ bo, float* __restrict__ z){
  __shared__ u32 h0[512], h1[512];
  int nx = blockIdx.x, bp = blockIdx.y, tid = threadIdx.x;
  int ba = bp * 2, bb = ba + 1;
  h0[tid] = y2p[ba * 512 + tid];       h1[tid] = y2p[bb * 512 + tid];
  h0[tid + 256] = y2p[ba * 512 + 256 + tid];
  h1[tid + 256] = y2p[bb * 512 + 256 + tid];
  __syncthreads();
  int n = nx * 250 + tid;
  if (tid >= 250) return;
  float a0 = 0.f, a1 = 0.f;
  #pragma unroll 8
  for (int p = 0; p < 512; p++){
    u32 w = Wop[p * C_ + n];
    a0 = fdot2u(w, h0[p], a0);
    a1 = fdot2u(w, h1[p], a1);
  }
  float bbv = bo[n];
  z[ba * C_ + n] = a0 + bbv;
  z[bb * C_ + n] = a1 + bbv;
}

// ---- N: softmax normalize. 64 blocks (1/batch) x 256 thr. ----
__global__ __launch_bounds__(256) void k_norm(const float* __restrict__ z,
                                              float* __restrict__ out){
  __shared__ float redm[4], reds[4];
  int b = blockIdx.x, tid = threadIdx.x;
  float z0 = z[b * C_ + tid];
  float z1 = z[b * C_ + 256 + tid];
  float z2 = z[b * C_ + 512 + tid];
  bool v3 = (768 + tid) < C_;
  float z3 = v3 ? z[b * C_ + 768 + tid] : -1e30f;
  float mx = fmaxf(fmaxf(z0, z1), fmaxf(z2, z3));
  #pragma unroll
  for (int o = 1; o < 64; o <<= 1) mx = fmaxf(mx, __shfl_xor(mx, o));
  if ((tid & 63) == 0) redm[tid >> 6] = mx;
  __syncthreads();
  mx = fmaxf(fmaxf(redm[0], redm[1]), fmaxf(redm[2], redm[3]));
  float e0 = __expf(z0 - mx), e1 = __expf(z1 - mx), e2 = __expf(z2 - mx);
  float e3 = v3 ? __expf(z3 - mx) : 0.f;
  float s = e0 + e1 + e2 + e3;
  #pragma unroll
  for (int o = 1; o < 64; o <<= 1) s += __shfl_xor(s, o);
  if ((tid & 63) == 0) reds[tid >> 6] = s;
  __syncthreads();
  s = reds[0] + reds[1] + reds[2] + reds[3];
  float inv = 1.0f / s;
  out[b * C_ + tid] = e0 * inv;
  out[b * C_ + 256 + tid] = e1 * inv;
  out[b * C_ + 512 + tid] = e2 * inv;
  if (v3) out[b * C_ + 768 + tid] = e3 * inv;
}

extern "C" void kernel_launch(void* const* d_in, const int* in_sizes, int n_in,
                              void* d_out, int out_size, void* d_ws, size_t ws_size,
                              hipStream_t stream) {
  const int*   tokens = (const int*)d_in[0];
  const float* emb    = (const float*)d_in[1];
  const float* Wx     = (const float*)d_in[2];
  const float* Wh     = (const float*)d_in[3];
  const float* brnn   = (const float*)d_in[4];
  const float* W1     = (const float*)d_in[5];
  const float* b1     = (const float*)d_in[6];
  const float* W2     = (const float*)d_in[7];
  const float* b2     = (const float*)d_in[8];
  const float* Wo     = (const float*)d_in[9];
  const float* bo     = (const float*)d_in[10];
  float* out = (float*)d_out;

  char* ws = (char*)d_ws;
  size_t off = 0;
  auto alloc = [&](size_t bytes) -> void* {
    void* p = ws + off;
    off += (bytes + 255) & ~(size_t)255;
    return p;
  };
  u16* WxT    = (u16*)alloc((size_t)512 * 512 * 2);
  u16* xpV    = (u16*)alloc((size_t)V_ * 512 * 2);
  uint4* Wf4  = (uint4*)alloc((size_t)128 * 64 * 16);
  u32* W1p    = (u32*)alloc((size_t)256 * 1024 * 4);
  u32* W2p    = (u32*)alloc((size_t)512 * 1024 * 4);
  u32* Wop    = (u32*)alloc((size_t)512 * 1000 * 4);
  u32* hpack  = (u32*)alloc((size_t)64 * 256 * 4);
  u32* y1p    = (u32*)alloc((size_t)64 * 512 * 4);
  u32* y2p    = (u32*)alloc((size_t)64 * 512 * 4);
  float* zbuf = (float*)alloc((size_t)64 * 1000 * 4);

  k_prep<<<dim3(96), dim3(256), 0, stream>>>(Wx, WxT, Wh, Wf4);
  k_gemm<<<dim3(3060), dim3(512), 0, stream>>>(emb, WxT, brnn, xpV,
                                               W1, W1p, W2, W2p, Wo, Wop);
  k_rnn<<<dim3(64), dim3(512), 0, stream>>>(Wf4, xpV, tokens, hpack);
  k_fc1<<<dim3(4, 32), dim3(256), 0, stream>>>(hpack, W1p, b1, y1p);
  k_fc2<<<dim3(4, 32), dim3(256), 0, stream>>>(y1p, W2p, b2, y2p);
  k_outz<<<dim3(4, 32), dim3(256), 0, stream>>>(y2p, Wop, bo, zbuf);
  k_norm<<<dim3(64), dim3(256), 0, stream>>>(zbuf, out);
}

// Round 11
// 377.344 us; speedup vs baseline: 1.2304x; 1.0242x over previous
//
#include <hip/hip_runtime.h>
#include <stdint.h>

typedef _Float16 half2_t __attribute__((ext_vector_type(2)));
typedef short bf16x8 __attribute__((ext_vector_type(8)));
typedef float f32x4 __attribute__((ext_vector_type(4)));
typedef int i32x4 __attribute__((ext_vector_type(4)));
typedef int i32x8 __attribute__((ext_vector_type(8)));
typedef unsigned short u16;
typedef unsigned int u32;
typedef unsigned long long u64;

#define B_ 64
#define S_ 512
#define D_ 512
#define H_ 512
#define FF_ 1024
#define C_ 1000
#define V_ 32000

// scaling: W' = 128*Wh (fp4 e2m1), g = 256*h (fp4, >=0).
#define SW4 128.0f
#define SH4 256.0f

__device__ __forceinline__ u16 f2bf(float f){
  u32 u = __builtin_bit_cast(u32, f);
  u = (u + 0x7FFFu + ((u >> 16) & 1u)) >> 16;
  return (u16)u;
}
__device__ __forceinline__ u32 pkbf(float a, float b){
  return (u32)f2bf(a) | ((u32)f2bf(b) << 16);
}
__device__ __forceinline__ u32 packh2(float a, float b){
  u16 lo = __builtin_bit_cast(u16, (_Float16)a);
  u16 hi = __builtin_bit_cast(u16, (_Float16)b);
  return (u32)lo | ((u32)hi << 16);
}
__device__ __forceinline__ float fdot2u(u32 a, u32 b, float c){
  return __builtin_amdgcn_fdot2(__builtin_bit_cast(half2_t, a),
                                __builtin_bit_cast(half2_t, b), c, false);
}
__device__ __forceinline__ float h2f(u16 h){
  return (float)__builtin_bit_cast(_Float16, h);
}
__device__ __forceinline__ float fp4val(u32 c){
  int e = (c >> 1) & 3;
  float m = 1.0f + 0.5f * (float)(c & 1);
  return (e == 0) ? 0.5f * (float)(c & 1) : m * (float)(1 << (e - 1));
}

// ---- P: Wx transpose+cvt [0,64) | Wh fp4 fragments [64,96) ----
__global__ void k_prep(const float* __restrict__ Wx, u16* __restrict__ WxT,
                       const float* __restrict__ Wh, uint4* __restrict__ Wf4){
  __shared__ u16 t[64][65];
  int bid = blockIdx.x, tid = threadIdx.x;
  if (bid < 64){
    int bx = bid & 7, by = bid >> 3;
    int c = tid & 63, r0 = (tid >> 6) * 16;
    #pragma unroll
    for (int i = 0; i < 16; i++){
      int k = by * 64 + r0 + i, n = bx * 64 + c;
      t[r0 + i][c] = f2bf(Wx[k * 512 + n]);
    }
    __syncthreads();
    #pragma unroll
    for (int i = 0; i < 16; i++){
      int n = bx * 64 + r0 + i, k = by * 64 + c;
      WxT[n * 512 + k] = t[c][r0 + i];
    }
  } else {
    int g = (bid - 64) * 256 + tid;            // 8192
    int fidx = g >> 6, l = g & 63;
    int wv = fidx >> 4, ct = (fidx >> 2) & 3, kt = fidx & 3;
    int q = l >> 4, n = wv * 64 + ct * 16 + (l & 15);
    int k0 = kt * 128 + q * 32;
    u32 d[4] = {0u, 0u, 0u, 0u};
    #pragma unroll
    for (int j = 0; j < 32; j++){
      float w = Wh[(size_t)(k0 + j) * 512 + n] * SW4;
      float aw = fabsf(w);
      u32 s = (w < 0.f) ? 8u : 0u;
      u32 c;
      if (aw < 2.f) c = (u32)(int)rintf(aw * 2.f);
      else if (aw < 4.f) c = 4u + (u32)(int)rintf(aw - 2.f);
      else { c = 6u + (u32)(int)rintf((aw - 4.f) * 0.5f); if (c > 7u) c = 7u; }
      d[j >> 3] |= (c | s) << (4 * (j & 7));
    }
    uint4 o; o.x = d[0]; o.y = d[1]; o.z = d[2]; o.w = d[3];
    Wf4[(size_t)fidx * 64 + l] = o;
  }
}

// ---- G: vocab GEMM [0,500) with reg double-buffered A stream, plus
// weight packs as extra blocks: W1 [500,1012), W2 [1012,2036), Wo [2036,3060).
__global__ __launch_bounds__(512) void k_gemm(const float* __restrict__ emb,
                                              const u16* __restrict__ WxT,
                                              const float* __restrict__ bias,
                                              u16* __restrict__ xpV,
                                              const float* __restrict__ W1, u32* __restrict__ W1p,
                                              const float* __restrict__ W2, u32* __restrict__ W2p,
                                              const float* __restrict__ Wo, u32* __restrict__ Wop){
  __shared__ __align__(16) u16 As[64 * 40];
  int bid = blockIdx.x, tid = threadIdx.x;
  if (bid >= 500){
    if (bid < 1012){
      int i = (bid - 500) * 512 + tid;         // 262144 = 256p x 1024n
      int p = i >> 10, n = i & 1023;
      W1p[p * FF_ + n] = packh2(W1[(2 * p) * FF_ + n], W1[(2 * p + 1) * FF_ + n]);
    } else if (bid < 2036){
      int i = (bid - 1012) * 512 + tid;        // 524288 = 512p x 1024n
      int p = i >> 10, n = i & 1023;
      W2p[p * FF_ + n] = packh2(W2[(2 * p) * FF_ + n], W2[(2 * p + 1) * FF_ + n]);
    } else {
      int i = (bid - 2036) * 512 + tid;        // 512p x 1024 (n<1000 valid)
      int p = i >> 10, n = i & 1023;
      if (n < C_)
        Wop[p * C_ + n] = packh2(Wo[(2 * p) * C_ + n], Wo[(2 * p + 1) * C_ + n]);
    }
    return;
  }
  int m0 = bid * 64;
  int w = tid >> 6, l = tid & 63, kg = l >> 4, r16 = l & 15;
  const u16* bptr[4];
  #pragma unroll
  for (int ni = 0; ni < 4; ni++)
    bptr[ni] = WxT + (size_t)(w * 64 + ni * 16 + r16) * 512 + kg * 8;
  f32x4 acc[4][4];
  #pragma unroll
  for (int mi = 0; mi < 4; mi++)
    #pragma unroll
    for (int ni = 0; ni < 4; ni++) acc[mi][ni] = (f32x4){0.f, 0.f, 0.f, 0.f};
  int srow = tid >> 3, sk = (tid & 7) * 4;
  const float* ebase = emb + (size_t)(m0 + srow) * 512 + sk;
  float4 f = *(const float4*)ebase;            // kt = 0
  for (int kt = 0; kt < 16; kt++){
    u32 lo = pkbf(f.x, f.y), hi = pkbf(f.z, f.w);
    float4 fn;
    if (kt < 15) fn = *(const float4*)(ebase + (kt + 1) * 32);   // prefetch
    __syncthreads();
    uint2 st; st.x = lo; st.y = hi;
    *(uint2*)(As + srow * 40 + sk) = st;
    __syncthreads();
    bf16x8 bfr[4], af[4];
    #pragma unroll
    for (int ni = 0; ni < 4; ni++)
      bfr[ni] = *(const bf16x8*)(bptr[ni] + kt * 32);
    #pragma unroll
    for (int mi = 0; mi < 4; mi++)
      af[mi] = *(const bf16x8*)(As + (mi * 16 + r16) * 40 + kg * 8);
    #pragma unroll
    for (int mi = 0; mi < 4; mi++)
      #pragma unroll
      for (int ni = 0; ni < 4; ni++)
        acc[mi][ni] = __builtin_amdgcn_mfma_f32_16x16x32_bf16(af[mi], bfr[ni], acc[mi][ni], 0, 0, 0);
    f = fn;
  }
  #pragma unroll
  for (int ni = 0; ni < 4; ni++){
    int col = w * 64 + ni * 16 + r16;
    float bb = bias[col];
    #pragma unroll
    for (int mi = 0; mi < 4; mi++){
      int mb = m0 + mi * 16 + kg * 4;
      #pragma unroll
      for (int r = 0; r < 4; r++){
        float v = (acc[mi][ni][r] + bb) * SH4;
        xpV[(size_t)(mb + r) * 512 + col] = __builtin_bit_cast(u16, (_Float16)v);
      }
    }
  }
}

// ---- R: 512-step RNN scan via MX-fp4 MFMA (K=128). 64 blocks x 512 thr. ----
// v2: t-loop unrolled x2 (static LDS buffers), s_setprio around MFMA cluster.
__global__ __launch_bounds__(512, 2) void k_rnn(
    const uint4* __restrict__ Wf4, const u16* __restrict__ xpV,
    const int* __restrict__ tokens, u32* __restrict__ hpack){
  __shared__ __align__(16) unsigned char gA[256];
  __shared__ __align__(16) unsigned char gB[256];
  __shared__ int toks[512];
  int b = blockIdx.x, tid = threadIdx.x;
  int wv = tid >> 6, l = tid & 63, q = l >> 4, n16 = l & 15;
  int col = wv * 64 + q * 16 + n16;

  i32x8 wgt[16];
  #pragma unroll
  for (int ct = 0; ct < 4; ct++)
    #pragma unroll
    for (int kt = 0; kt < 4; kt++){
      int fidx = (wv * 4 + ct) * 4 + kt;
      uint4 wl = Wf4[(size_t)fidx * 64 + l];
      i32x8 w8 = {(int)wl.x, (int)wl.y, (int)wl.z, (int)wl.w, 0, 0, 0, 0};
      wgt[ct * 4 + kt] = w8;
    }

  toks[tid] = tokens[b * 512 + tid];
  if (tid < 64) ((u32*)gA)[tid] = 0;
  __syncthreads();

  const u16* xpc = xpV + col;                  // lane's column base
  u16 xraw = xpc[(size_t)toks[0] * 512];
  u32 greg = 0;

#define RNN_STEP(T, SRC, DST)                                                 \
  {                                                                           \
    int tn = toks[(T + 1) & 511];                                             \
    u16 xnext = xpc[(size_t)tn * 512];                                        \
    bool wr = toks[T] != 0;                                                   \
    i32x4 av0 = *(const i32x4*)(SRC + 0 * 64 + q * 16);                       \
    i32x4 av1 = *(const i32x4*)(SRC + 1 * 64 + q * 16);                       \
    i32x4 av2 = *(const i32x4*)(SRC + 2 * 64 + q * 16);                       \
    i32x4 av3 = *(const i32x4*)(SRC + 3 * 64 + q * 16);                       \
    i32x8 a80 = {av0[0], av0[1], av0[2], av0[3], 0, 0, 0, 0};                 \
    i32x8 a81 = {av1[0], av1[1], av1[2], av1[3], 0, 0, 0, 0};                 \
    i32x8 a82 = {av2[0], av2[1], av2[2], av2[3], 0, 0, 0, 0};                 \
    i32x8 a83 = {av3[0], av3[1], av3[2], av3[3], 0, 0, 0, 0};                 \
    f32x4 acc0 = {0.f,0.f,0.f,0.f}, acc1 = {0.f,0.f,0.f,0.f};                 \
    f32x4 acc2 = {0.f,0.f,0.f,0.f}, acc3 = {0.f,0.f,0.f,0.f};                 \
    __builtin_amdgcn_s_setprio(1);                                            \
    acc0 = __builtin_amdgcn_mfma_scale_f32_16x16x128_f8f6f4(a80, wgt[0],  acc0, 4, 4, 0, 127, 0, 127); \
    acc1 = __builtin_amdgcn_mfma_scale_f32_16x16x128_f8f6f4(a80, wgt[4],  acc1, 4, 4, 0, 127, 0, 127); \
    acc2 = __builtin_amdgcn_mfma_scale_f32_16x16x128_f8f6f4(a80, wgt[8],  acc2, 4, 4, 0, 127, 0, 127); \
    acc3 = __builtin_amdgcn_mfma_scale_f32_16x16x128_f8f6f4(a80, wgt[12], acc3, 4, 4, 0, 127, 0, 127); \
    acc0 = __builtin_amdgcn_mfma_scale_f32_16x16x128_f8f6f4(a81, wgt[1],  acc0, 4, 4, 0, 127, 0, 127); \
    acc1 = __builtin_amdgcn_mfma_scale_f32_16x16x128_f8f6f4(a81, wgt[5],  acc1, 4, 4, 0, 127, 0, 127); \
    acc2 = __builtin_amdgcn_mfma_scale_f32_16x16x128_f8f6f4(a81, wgt[9],  acc2, 4, 4, 0, 127, 0, 127); \
    acc3 = __builtin_amdgcn_mfma_scale_f32_16x16x128_f8f6f4(a81, wgt[13], acc3, 4, 4, 0, 127, 0, 127); \
    acc0 = __builtin_amdgcn_mfma_scale_f32_16x16x128_f8f6f4(a82, wgt[2],  acc0, 4, 4, 0, 127, 0, 127); \
    acc1 = __builtin_amdgcn_mfma_scale_f32_16x16x128_f8f6f4(a82, wgt[6],  acc1, 4, 4, 0, 127, 0, 127); \
    acc2 = __builtin_amdgcn_mfma_scale_f32_16x16x128_f8f6f4(a82, wgt[10], acc2, 4, 4, 0, 127, 0, 127); \
    acc3 = __builtin_amdgcn_mfma_scale_f32_16x16x128_f8f6f4(a82, wgt[14], acc3, 4, 4, 0, 127, 0, 127); \
    acc0 = __builtin_amdgcn_mfma_scale_f32_16x16x128_f8f6f4(a83, wgt[3],  acc0, 4, 4, 0, 127, 0, 127); \
    acc1 = __builtin_amdgcn_mfma_scale_f32_16x16x128_f8f6f4(a83, wgt[7],  acc1, 4, 4, 0, 127, 0, 127); \
    acc2 = __builtin_amdgcn_mfma_scale_f32_16x16x128_f8f6f4(a83, wgt[11], acc2, 4, 4, 0, 127, 0, 127); \
    acc3 = __builtin_amdgcn_mfma_scale_f32_16x16x128_f8f6f4(a83, wgt[15], acc3, 4, 4, 0, 127, 0, 127); \
    __builtin_amdgcn_s_setprio(0);                                            \
    float av = (q == 0) ? acc0[0] : (q == 1) ? acc1[0] : (q == 2) ? acc2[0] : acc3[0]; \
    float gn = fmaxf(fmaf(av, 1.0f / SW4, h2f(xraw)), 0.f);                   \
    u32 code;                                                                 \
    if (gn < 2.f) code = (u32)(int)rintf(gn * 2.f);                           \
    else if (gn < 4.f) code = 4u + (u32)(int)rintf(gn - 2.f);                 \
    else { u32 c = 6u + (u32)(int)rintf((gn - 4.f) * 0.5f); code = c > 7u ? 7u : c; } \
    u32 pc = (u32)__shfl_xor((int)code, 1);                                   \
    u32 byte = (n16 & 1) ? (pc | (code << 4)) : (code | (pc << 4));           \
    if (wr) greg = byte;                                                      \
    if ((l & 1) == 0) DST[col >> 1] = (unsigned char)greg;                    \
    xraw = xnext;                                                             \
  }

  #pragma unroll 1
  for (int t = 0; t < 512; t += 2){
    RNN_STEP(t, gA, gB);
    __syncthreads();
    RNN_STEP(t + 1, gB, gA);
    __syncthreads();
  }
#undef RNN_STEP

  if (tid < 256){
    u32 byte = gA[tid];
    float f0 = fp4val(byte & 15u) * (1.0f / SH4);
    float f1 = fp4val(byte >> 4) * (1.0f / SH4);
    hpack[b * 256 + tid] = packh2(f0, f1);
  }
}

// ---- F1: y1 = relu(h @ W1 + b1). grid (4 nslices, 32 batch-pairs). ----
__global__ __launch_bounds__(256) void k_fc1(const u32* __restrict__ hpack,
    const u32* __restrict__ W1p, const float* __restrict__ b1, u32* __restrict__ y1p){
  __shared__ u32 h0[256], h1[256];
  int nx = blockIdx.x, bp = blockIdx.y, tid = threadIdx.x;
  int ba = bp * 2, bb = ba + 1;
  int n = nx * 256 + tid;
  h0[tid] = hpack[ba * 256 + tid];
  h1[tid] = hpack[bb * 256 + tid];
  __syncthreads();
  float a0 = 0.f, a1 = 0.f;
  #pragma unroll 8
  for (int p = 0; p < 256; p++){
    u32 w = W1p[p * FF_ + n];
    a0 = fdot2u(w, h0[p], a0);
    a1 = fdot2u(w, h1[p], a1);
  }
  float bbv = b1[n];
  float y0 = fmaxf(a0 + bbv, 0.f), y1 = fmaxf(a1 + bbv, 0.f);
  float o0 = __shfl_xor(y0, 1), o1 = __shfl_xor(y1, 1);
  if (!(tid & 1)){
    y1p[ba * 512 + (n >> 1)] = packh2(y0, o0);
    y1p[bb * 512 + (n >> 1)] = packh2(y1, o1);
  }
}

// ---- F2: y2 = relu(y1 @ W2 + b2). grid (4, 32). ----
__global__ __launch_bounds__(256) void k_fc2(const u32* __restrict__ y1p,
    const u32* __restrict__ W2p, const float* __restrict__ b2, u32* __restrict__ y2p){
  __shared__ u32 h0[512], h1[512];
  int nx = blockIdx.x, bp = blockIdx.y, tid = threadIdx.x;
  int ba = bp * 2, bb = ba + 1;
  int n = nx * 256 + tid;
  h0[tid] = y1p[ba * 512 + tid];       h1[tid] = y1p[bb * 512 + tid];
  h0[tid + 256] = y1p[ba * 512 + 256 + tid];
  h1[tid + 256] = y1p[bb * 512 + 256 + tid];
  __syncthreads();
  float a0 = 0.f, a1 = 0.f;
  #pragma unroll 8
  for (int p = 0; p < 512; p++){
    u32 w = W2p[p * FF_ + n];
    a0 = fdot2u(w, h0[p], a0);
    a1 = fdot2u(w, h1[p], a1);
  }
  float bbv = b2[n];
  float y0 = fmaxf(a0 + bbv, 0.f), y1 = fmaxf(a1 + bbv, 0.f);
  float o0 = __shfl_xor(y0, 1), o1 = __shfl_xor(y1, 1);
  if (!(tid & 1)){
    y2p[ba * 512 + (n >> 1)] = packh2(y0, o0);
    y2p[bb * 512 + (n >> 1)] = packh2(y1, o1);
  }
}

// ---- OZ: z = y2 @ Wo + bo (logits, f32). grid (4 cslices, 32 pairs). ----
__global__ __launch_bounds__(256) void k_outz(const u32* __restrict__ y2p,
    const u32* __restrict__ Wop, const float* __restrict__ bo, float* __restrict__ z){
  __shared__ u32 h0[512], h1[512];
  int nx = blockIdx.x, bp = blockIdx.y, tid = threadIdx.x;
  int ba = bp * 2, bb = ba + 1;
  h0[tid] = y2p[ba * 512 + tid];       h1[tid] = y2p[bb * 512 + tid];
  h0[tid + 256] = y2p[ba * 512 + 256 + tid];
  h1[tid + 256] = y2p[bb * 512 + 256 + tid];
  __syncthreads();
  int n = nx * 250 + tid;
  if (tid >= 250) return;
  float a0 = 0.f, a1 = 0.f;
  #pragma unroll 8
  for (int p = 0; p < 512; p++){
    u32 w = Wop[p * C_ + n];
    a0 = fdot2u(w, h0[p], a0);
    a1 = fdot2u(w, h1[p], a1);
  }
  float bbv = bo[n];
  z[ba * C_ + n] = a0 + bbv;
  z[bb * C_ + n] = a1 + bbv;
}

// ---- N: softmax normalize. 64 blocks (1/batch) x 256 thr. ----
__global__ __launch_bounds__(256) void k_norm(const float* __restrict__ z,
                                              float* __restrict__ out){
  __shared__ float redm[4], reds[4];
  int b = blockIdx.x, tid = threadIdx.x;
  float z0 = z[b * C_ + tid];
  float z1 = z[b * C_ + 256 + tid];
  float z2 = z[b * C_ + 512 + tid];
  bool v3 = (768 + tid) < C_;
  float z3 = v3 ? z[b * C_ + 768 + tid] : -1e30f;
  float mx = fmaxf(fmaxf(z0, z1), fmaxf(z2, z3));
  #pragma unroll
  for (int o = 1; o < 64; o <<= 1) mx = fmaxf(mx, __shfl_xor(mx, o));
  if ((tid & 63) == 0) redm[tid >> 6] = mx;
  __syncthreads();
  mx = fmaxf(fmaxf(redm[0], redm[1]), fmaxf(redm[2], redm[3]));
  float e0 = __expf(z0 - mx), e1 = __expf(z1 - mx), e2 = __expf(z2 - mx);
  float e3 = v3 ? __expf(z3 - mx) : 0.f;
  float s = e0 + e1 + e2 + e3;
  #pragma unroll
  for (int o = 1; o < 64; o <<= 1) s += __shfl_xor(s, o);
  if ((tid & 63) == 0) reds[tid >> 6] = s;
  __syncthreads();
  s = reds[0] + reds[1] + reds[2] + reds[3];
  float inv = 1.0f / s;
  out[b * C_ + tid] = e0 * inv;
  out[b * C_ + 256 + tid] = e1 * inv;
  out[b * C_ + 512 + tid] = e2 * inv;
  if (v3) out[b * C_ + 768 + tid] = e3 * inv;
}

extern "C" void kernel_launch(void* const* d_in, const int* in_sizes, int n_in,
                              void* d_out, int out_size, void* d_ws, size_t ws_size,
                              hipStream_t stream) {
  const int*   tokens = (const int*)d_in[0];
  const float* emb    = (const float*)d_in[1];
  const float* Wx     = (const float*)d_in[2];
  const float* Wh     = (const float*)d_in[3];
  const float* brnn   = (const float*)d_in[4];
  const float* W1     = (const float*)d_in[5];
  const float* b1     = (const float*)d_in[6];
  const float* W2     = (const float*)d_in[7];
  const float* b2     = (const float*)d_in[8];
  const float* Wo     = (const float*)d_in[9];
  const float* bo     = (const float*)d_in[10];
  float* out = (float*)d_out;

  char* ws = (char*)d_ws;
  size_t off = 0;
  auto alloc = [&](size_t bytes) -> void* {
    void* p = ws + off;
    off += (bytes + 255) & ~(size_t)255;
    return p;
  };
  u16* WxT    = (u16*)alloc((size_t)512 * 512 * 2);
  u16* xpV    = (u16*)alloc((size_t)V_ * 512 * 2);
  uint4* Wf4  = (uint4*)alloc((size_t)128 * 64 * 16);
  u32* W1p    = (u32*)alloc((size_t)256 * 1024 * 4);
  u32* W2p    = (u32*)alloc((size_t)512 * 1024 * 4);
  u32* Wop    = (u32*)alloc((size_t)512 * 1000 * 4);
  u32* hpack  = (u32*)alloc((size_t)64 * 256 * 4);
  u32* y1p    = (u32*)alloc((size_t)64 * 512 * 4);
  u32* y2p    = (u32*)alloc((size_t)64 * 512 * 4);
  float* zbuf = (float*)alloc((size_t)64 * 1000 * 4);

  k_prep<<<dim3(96), dim3(256), 0, stream>>>(Wx, WxT, Wh, Wf4);
  k_gemm<<<dim3(3060), dim3(512), 0, stream>>>(emb, WxT, brnn, xpV,
                                               W1, W1p, W2, W2p, Wo, Wop);
  k_rnn<<<dim3(64), dim3(512), 0, stream>>>(Wf4, xpV, tokens, hpack);
  k_fc1<<<dim3(4, 32), dim3(256), 0, stream>>>(hpack, W1p, b1, y1p);
  k_fc2<<<dim3(4, 32), dim3(256), 0, stream>>>(y1p, W2p, b2, y2p);
  k_outz<<<dim3(4, 32), dim3(256), 0, stream>>>(y2p, Wop, bo, zbuf);
  k_norm<<<dim3(64), dim3(256), 0, stream>>>(zbuf, out);
}